// Round 19
// baseline (180.458 us; speedup 1.0000x reference)
//
#include <hip/hip_runtime.h>

// GraphTransformerBlock2: GATConv(H=3,C=64, edge_dim=5, self-loops w/ mean fill)
// -> linear1 -> LN(x + .) -> linear2 -> LN(lin + .)
// All float32 I/O. edge_index int32 (2,E): src=ei[0:E], dst=ei[E:2E].
//
// R18: (a) a_src/a_dst folded into k_xs's MFMA: linwt extended to 13 col-tiles
//      (cols 192..194 = lin_w@att_src * log2e, 195..197 = lin_w@att_dst * log2e,
//      198..207 zero) -> epilogue shuffle reductions deleted entirely.
//      (b) k_gatmlp phase-B unroll 3 -> 4 (8 gathers in flight; VGPR ~46 < 64
//      wave-cap budget). R17 pipelining kept (neutral, harmless).

#define HH 3
#define CC 64
#define DIN 64
#define ED 5
#define HC 192
#define LWC 208                 // extended linwt cols (13 tiles of 16)
#define OAP 200                 // padded OA row stride (u16)
#define NEG_SLOPE 0.2f
#define LN_EPS 1e-5f
#define LOG2E 1.44269504f

typedef __attribute__((ext_vector_type(8))) short bf16x8;
typedef __attribute__((ext_vector_type(4))) float f32x4;

__device__ __forceinline__ float leaky(float l) { return fmaxf(l, NEG_SLOPE * l); }

__device__ __forceinline__ unsigned short f2bf(float f) {
    unsigned u = __float_as_uint(f);
    unsigned r = (u + 0x7FFFu + ((u >> 16) & 1u)) >> 16;   // RNE
    return (unsigned short)r;
}
__device__ __forceinline__ float bf2f(unsigned short u) {
    return __uint_as_float((unsigned)u << 16);
}
__device__ __forceinline__ float bf_lo(unsigned v) { return __uint_as_float(v << 16); }
__device__ __forceinline__ float bf_hi(unsigned v) { return __uint_as_float(v & 0xFFFF0000u); }

__device__ __forceinline__ bf16x8 pack8(float4 a, float4 b) {
    bf16x8 r;
    r[0] = (short)f2bf(a.x); r[1] = (short)f2bf(a.y);
    r[2] = (short)f2bf(a.z); r[3] = (short)f2bf(a.w);
    r[4] = (short)f2bf(b.x); r[5] = (short)f2bf(b.y);
    r[6] = (short)f2bf(b.z); r[7] = (short)f2bf(b.w);
    return r;
}

// ---------- prep: transposes (blocks 0..27), folds (block 28), cnt (rest) ----------
#define PREP_TRANS (HC*DIN + DIN*HC + CC*CC)
#define PREP_BLOCKS 28
__global__ __launch_bounds__(256) void k_prep_cnt(const float* __restrict__ lin_w,
                                                  const float* __restrict__ w1,
                                                  const float* __restrict__ w2,
                                                  const float* __restrict__ b1,
                                                  const float* __restrict__ gat_bias,
                                                  const float* __restrict__ lin_edge_w,
                                                  const float* __restrict__ att_edge,
                                                  const float* __restrict__ att_src,
                                                  const float* __restrict__ att_dst,
                                                  unsigned short* __restrict__ linwt,
                                                  unsigned short* __restrict__ w1t,
                                                  unsigned short* __restrict__ w2t,
                                                  float* __restrict__ b1p,
                                                  float* __restrict__ we,
                                                  const int* __restrict__ ei,
                                                  int* __restrict__ icnt, int E) {
    if (blockIdx.x < PREP_BLOCKS) {
        for (int i = blockIdx.x * 256 + threadIdx.x; i < PREP_TRANS; i += PREP_BLOCKS * 256) {
            if (i < HC * DIN) {
                int c = i >> 6, k = i & 63;
                linwt[i] = f2bf(lin_w[k * HC + c]);
            } else if (i < 2 * HC * DIN) {
                int j = i - HC * DIN;
                int c = j / HC, k = j - c * HC;
                w1t[j] = f2bf(w1[k * CC + c]);
            } else {
                int j = i - 2 * HC * DIN;
                int c = j >> 6, k = j & 63;
                w2t[j] = f2bf(w2[k * CC + c]);
            }
        }
    } else if (blockIdx.x == PREP_BLOCKS) {
        __shared__ float pb[4][CC];
        __shared__ float pw[15][16];
        int t = threadIdx.x;
        int c = t & 63, kq = t >> 6;
        float s = 0.f;
        for (int k = kq * 48; k < kq * 48 + 48; ++k)
            s += gat_bias[k] * w1[k * CC + c];
        pb[kq][c] = s;
        int q = t >> 4, cq = t & 15;
        if (q < 15) {
            int d = q / HH, h = q - d * HH;
            float s2 = 0.f;
            #pragma unroll
            for (int c2 = cq * 4; c2 < cq * 4 + 4; ++c2)
                s2 += lin_edge_w[d * HC + h * CC + c2] * att_edge[h * CC + c2];
            pw[q][cq] = s2;
        }
        // extended linwt cols 192..207: wsf (a_src fold), wdf (a_dst fold), zeros
        for (int idx = t; idx < 16 * DIN; idx += 256) {
            int col = idx >> 6;          // 0..15
            int d = idx & 63;
            float v = 0.f;
            if (col < 6) {
                int h = (col < 3) ? col : col - 3;
                const float* att = (col < 3) ? att_src : att_dst;
                for (int c2 = 0; c2 < CC; ++c2)
                    v += lin_w[d * HC + h * CC + c2] * att[h * CC + c2];
                v *= LOG2E;
            }
            linwt[(size_t)(HC + col) * DIN + d] = f2bf(v);
        }
        __syncthreads();
        if (t < CC) b1p[t] = b1[t] + pb[0][t] + pb[1][t] + pb[2][t] + pb[3][t];
        if (t < 15) {
            float tot = 0.f;
            #pragma unroll
            for (int i2 = 0; i2 < 16; ++i2) tot += pw[t][i2];
            we[t] = tot * LOG2E;
        }
    } else {
        int nb = gridDim.x - PREP_BLOCKS - 1;
        for (int e = (blockIdx.x - PREP_BLOCKS - 1) * 256 + threadIdx.x; e < E; e += nb * 256)
            atomicAdd(&icnt[ei[E + e]], 1);
    }
}

// ---------- xs = x @ [lin_w | folds] (MFMA, 13 tiles) -> xsb + a_src/a_dst; scan fused ----------
__global__ __launch_bounds__(256) void k_xs(const float* __restrict__ x,
                                            const unsigned short* __restrict__ linwt,
                                            unsigned short* __restrict__ xsb,
                                            float* __restrict__ a_src,
                                            float* __restrict__ a_dst,
                                            const int* __restrict__ icnt,
                                            int* __restrict__ gtot,
                                            int* __restrict__ off,
                                            int* __restrict__ cursor,
                                            int N, int nbx) {
    __shared__ int wt[4];
    __shared__ int base_sh;
    if ((int)blockIdx.x >= nbx) {
        int bid = blockIdx.x - nbx;
        int i = bid * 256 + threadIdx.x;
        int lane = threadIdx.x & 63, wid = threadIdx.x >> 6;
        int v = (i < N) ? icnt[i] : 0;
        int incl = v;
        #pragma unroll
        for (int o = 1; o < 64; o <<= 1) {
            int u = __shfl_up(incl, o, 64);
            if (lane >= o) incl += u;
        }
        if (lane == 63) wt[wid] = incl;
        __syncthreads();
        if (threadIdx.x == 0)
            base_sh = atomicAdd(gtot, wt[0] + wt[1] + wt[2] + wt[3]);
        __syncthreads();
        int wpre = 0;
        for (int w2 = 0; w2 < wid; ++w2) wpre += wt[w2];
        int excl = base_sh + wpre + incl - v;
        if (i < N) { off[i] = excl; cursor[i] = excl; }
        return;
    }

    int lane = threadIdx.x & 63, w = threadIdx.x >> 6;
    int l15 = lane & 15, kg = (lane >> 4) * 8;
    int nb = blockIdx.x * 64;
    int arow = nb + w * 16 + l15;
    int arow_c = min(arow, N - 1);

    f32x4 acc[13];
    #pragma unroll
    for (int ct = 0; ct < 13; ++ct) acc[ct] = (f32x4){0.f, 0.f, 0.f, 0.f};

    #pragma unroll
    for (int k0 = 0; k0 < DIN; k0 += 32) {
        const float* ap = x + (size_t)arow_c * DIN + k0 + kg;
        float4 a0 = *(const float4*)ap;
        float4 a1 = *(const float4*)(ap + 4);
        bf16x8 af = pack8(a0, a1);
        #pragma unroll
        for (int ct = 0; ct < 13; ++ct) {
            bf16x8 bf = *(const bf16x8*)(linwt + (size_t)(ct * 16 + l15) * DIN + k0 + kg);
            acc[ct] = __builtin_amdgcn_mfma_f32_16x16x32_bf16(af, bf, acc[ct], 0, 0, 0);
        }
    }

    int rbase = nb + w * 16 + (lane >> 4) * 4;
    #pragma unroll
    for (int j = 0; j < 4; ++j) {
        int r = rbase + j;
        bool ok = r < N;
        if (ok) {
            unsigned* row32 = (unsigned*)(xsb + (size_t)r * HC);
            #pragma unroll
            for (int ct = 0; ct < 4; ++ct) {
                int c = ct * 16 + l15;
                row32[c] = (unsigned)f2bf(acc[ct][j]) | ((unsigned)f2bf(acc[ct + 4][j]) << 16);
                xsb[(size_t)r * HC + 128 + c] = f2bf(acc[ct + 8][j]);
            }
            // tile 12: cols 192..197 = a_src[0..2], a_dst[0..2] (pre-scaled by log2e)
            if (l15 < 3)           a_src[r * HH + l15] = acc[12][j];
            else if (l15 < 6)      a_dst[r * HH + (l15 - 3)] = acc[12][j];
        }
    }
}

// ---------- payload fill (CSR order), 16B/edge, a_dst FOLDED IN ----------
__global__ __launch_bounds__(256) void k_fill(const float* __restrict__ ea,
                                              const int* __restrict__ ei,
                                              const float* __restrict__ a_src,
                                              const float* __restrict__ a_dst,
                                              const float* __restrict__ we,
                                              int* __restrict__ cursor,
                                              uint4* __restrict__ payload, int E) {
    int e = blockIdx.x * blockDim.x + threadIdx.x;
    if (e >= E) return;
    int s = ei[e], d = ei[E + e];
    int pos = atomicAdd(&cursor[d], 1);                  // issue early; hide RMW latency
    float attr[ED];
    #pragma unroll
    for (int j = 0; j < ED; ++j) attr[j] = ea[(size_t)e * ED + j];
    float aeh[HH], lp[HH];
    #pragma unroll
    for (int h = 0; h < HH; ++h) {
        float a = 0.f;
        #pragma unroll
        for (int j = 0; j < ED; ++j) a += attr[j] * we[j * HH + h];   // we pre-scaled
        aeh[h] = a;
        lp[h] = a_src[s * HH + h] + a_dst[d * HH + h] + a;             // all pre-scaled
    }
    uint4 pk;
    pk.x = (unsigned)f2bf(lp[0])  | ((unsigned)f2bf(lp[1])  << 16);
    pk.y = (unsigned)f2bf(lp[2])  | ((unsigned)f2bf(aeh[0]) << 16);
    pk.z = (unsigned)f2bf(aeh[1]) | ((unsigned)f2bf(aeh[2]) << 16);
    pk.w = (unsigned)s;
    payload[pos] = pk;
}

// ---------- FUSED: per-dst softmax+gather (pipelined, 4-wide) -> MLP -> out ----------
__global__ __launch_bounds__(256) void k_gatmlp(const unsigned short* __restrict__ xsb,
                                                const float* __restrict__ a_src,
                                                const float* __restrict__ a_dst,
                                                const int* __restrict__ off,
                                                const int* __restrict__ icnt,
                                                const uint4* __restrict__ payload,
                                                const float* __restrict__ x,
                                                const unsigned short* __restrict__ w1t,
                                                const unsigned short* __restrict__ w2t,
                                                const float* __restrict__ b1p,
                                                const float* __restrict__ g1,
                                                const float* __restrict__ be1,
                                                const float* __restrict__ b2,
                                                const float* __restrict__ g2,
                                                const float* __restrict__ be2,
                                                float* __restrict__ out, int N) {
    __shared__ float4 wbuf[4][64];                 // 4 KB
    __shared__ unsigned short OA[16 * OAP];        // 6.25 KB, padded stride
    __shared__ unsigned short H1s[16 * 72];        // 2.25 KB
    __shared__ float red[2][4][16];                // 512 B
    int lane = threadIdx.x & 63;
    int wid  = threadIdx.x >> 6;
    const unsigned* xs32 = (const unsigned*)xsb;
    unsigned c128ml = 128u - (unsigned)lane;
    int nb16 = blockIdx.x * 16;
    int n0 = nb16 + wid * 4;

    // ---- pipeline prologue: node 0's descriptor + first payload chunk ----
    int begC = 0, degC = 0;
    if (n0 < N) { begC = off[n0]; degC = icnt[n0]; }
    uint4 pC; pC.x = 0; pC.y = 0; pC.z = 0; pC.w = 0;
    if (lane < degC) pC = payload[begC + lane];

    // ======== gather phase: 4 nodes, software-pipelined, 4-wide phase B ========
    #pragma unroll 1
    for (int t = 0; t < 4; ++t) {
        int row = wid * 4 + t;
        int n = n0 + t;
        int begNx = 0, degNx = 0;
        if (t < 3) {
            int nn = n + 1;
            if (nn < N) { begNx = off[nn]; degNx = icnt[nn]; }
        }
        int beg = begC, deg = degC;
        uint4 p0 = pC;

        if (n < N) {
            float pden0 = 0.f, pden1 = 0.f, pden2 = 0.f;
            float pae0 = 0.f, pae1 = 0.f, pae2 = 0.f;
            float a0A = 0.f, a1A = 0.f, a2A = 0.f;
            float a0B = 0.f, a1B = 0.f, a2B = 0.f;
            float a0C = 0.f, a1C = 0.f, a2C = 0.f;
            float a0D = 0.f, a1D = 0.f, a2D = 0.f;

            // ---- chunk 0 (peeled, payload already in p0) ----
            {
                int cn = min(deg, 64);
                float w0 = 0.f, w1 = 0.f, w2 = 0.f;
                int src = 0;
                if (lane < cn) {
                    w0 = exp2f(leaky(bf_lo(p0.x)));
                    w1 = exp2f(leaky(bf_hi(p0.x)));
                    w2 = exp2f(leaky(bf_lo(p0.y)));
                    pae0 += bf_hi(p0.y);
                    pae1 += bf_lo(p0.z);
                    pae2 += bf_hi(p0.z);
                    pden0 += w0; pden1 += w1; pden2 += w2;
                    src = (int)p0.w;
                }
                wbuf[wid][lane] = make_float4(w0, w1, w2, __int_as_float(src));
                if (t < 3) {
                    pC.x = 0; pC.y = 0; pC.z = 0; pC.w = 0;
                    if (lane < degNx) pC = payload[begNx + lane];
                }
                int i = 0;
                for (; i + 4 <= cn; i += 4) {
                    float4 ta = wbuf[wid][i];
                    float4 tb = wbuf[wid][i + 1];
                    float4 tc = wbuf[wid][i + 2];
                    float4 td = wbuf[wid][i + 3];
                    unsigned ia = __umul24((unsigned)__float_as_int(ta.w), 96u) + lane;
                    unsigned ib = __umul24((unsigned)__float_as_int(tb.w), 96u) + lane;
                    unsigned ic = __umul24((unsigned)__float_as_int(tc.w), 96u) + lane;
                    unsigned id = __umul24((unsigned)__float_as_int(td.w), 96u) + lane;
                    unsigned va = xs32[ia];
                    unsigned vb = xs32[ib];
                    unsigned vc = xs32[ic];
                    unsigned vd = xs32[id];
                    float xa2 = bf2f(xsb[(ia << 1) + c128ml]);
                    float xb2 = bf2f(xsb[(ib << 1) + c128ml]);
                    float xc2 = bf2f(xsb[(ic << 1) + c128ml]);
                    float xd2 = bf2f(xsb[(id << 1) + c128ml]);
                    a0A += ta.x * bf_lo(va); a1A += ta.y * bf_hi(va); a2A += ta.z * xa2;
                    a0B += tb.x * bf_lo(vb); a1B += tb.y * bf_hi(vb); a2B += tb.z * xb2;
                    a0C += tc.x * bf_lo(vc); a1C += tc.y * bf_hi(vc); a2C += tc.z * xc2;
                    a0D += td.x * bf_lo(vd); a1D += td.y * bf_hi(vd); a2D += td.z * xd2;
                }
                for (; i < cn; ++i) {
                    float4 ta = wbuf[wid][i];
                    unsigned ia = __umul24((unsigned)__float_as_int(ta.w), 96u) + lane;
                    unsigned va = xs32[ia];
                    a0A += ta.x * bf_lo(va);
                    a1A += ta.y * bf_hi(va);
                    a2A += ta.z * bf2f(xsb[(ia << 1) + c128ml]);
                }
            }
            // ---- remaining chunks (rare: deg > 64) ----
            for (int c0 = 64; c0 < deg; c0 += 64) {
                int cn = min(deg - c0, 64);
                float w0 = 0.f, w1 = 0.f, w2 = 0.f;
                int src = 0;
                if (lane < cn) {
                    uint4 p = payload[beg + c0 + lane];
                    w0 = exp2f(leaky(bf_lo(p.x)));
                    w1 = exp2f(leaky(bf_hi(p.x)));
                    w2 = exp2f(leaky(bf_lo(p.y)));
                    pae0 += bf_hi(p.y);
                    pae1 += bf_lo(p.z);
                    pae2 += bf_hi(p.z);
                    pden0 += w0; pden1 += w1; pden2 += w2;
                    src = (int)p.w;
                }
                wbuf[wid][lane] = make_float4(w0, w1, w2, __int_as_float(src));
                int i = 0;
                for (; i + 4 <= cn; i += 4) {
                    float4 ta = wbuf[wid][i];
                    float4 tb = wbuf[wid][i + 1];
                    float4 tc = wbuf[wid][i + 2];
                    float4 td = wbuf[wid][i + 3];
                    unsigned ia = __umul24((unsigned)__float_as_int(ta.w), 96u) + lane;
                    unsigned ib = __umul24((unsigned)__float_as_int(tb.w), 96u) + lane;
                    unsigned ic = __umul24((unsigned)__float_as_int(tc.w), 96u) + lane;
                    unsigned id = __umul24((unsigned)__float_as_int(td.w), 96u) + lane;
                    unsigned va = xs32[ia];
                    unsigned vb = xs32[ib];
                    unsigned vc = xs32[ic];
                    unsigned vd = xs32[id];
                    float xa2 = bf2f(xsb[(ia << 1) + c128ml]);
                    float xb2 = bf2f(xsb[(ib << 1) + c128ml]);
                    float xc2 = bf2f(xsb[(ic << 1) + c128ml]);
                    float xd2 = bf2f(xsb[(id << 1) + c128ml]);
                    a0A += ta.x * bf_lo(va); a1A += ta.y * bf_hi(va); a2A += ta.z * xa2;
                    a0B += tb.x * bf_lo(vb); a1B += tb.y * bf_hi(vb); a2B += tb.z * xb2;
                    a0C += tc.x * bf_lo(vc); a1C += tc.y * bf_hi(vc); a2C += tc.z * xc2;
                    a0D += td.x * bf_lo(vd); a1D += td.y * bf_hi(vd); a2D += td.z * xd2;
                }
                for (; i < cn; ++i) {
                    float4 ta = wbuf[wid][i];
                    unsigned ia = __umul24((unsigned)__float_as_int(ta.w), 96u) + lane;
                    unsigned va = xs32[ia];
                    a0A += ta.x * bf_lo(va);
                    a1A += ta.y * bf_hi(va);
                    a2A += ta.z * bf2f(xsb[(ia << 1) + c128ml]);
                }
            }

            #pragma unroll
            for (int o = 32; o; o >>= 1) {
                pden0 += __shfl_xor(pden0, o, 64);
                pden1 += __shfl_xor(pden1, o, 64);
                pden2 += __shfl_xor(pden2, o, 64);
                pae0  += __shfl_xor(pae0, o, 64);
                pae1  += __shfl_xor(pae1, o, 64);
                pae2  += __shfl_xor(pae2, o, 64);
            }

            float dc = fmaxf((float)deg, 1.0f);
            float inv_dc = __builtin_amdgcn_rcpf(dc);
            float sl0 = leaky(a_src[n * HH + 0] + a_dst[n * HH + 0] + pae0 * inv_dc);
            float sl1 = leaky(a_src[n * HH + 1] + a_dst[n * HH + 1] + pae1 * inv_dc);
            float sl2 = leaky(a_src[n * HH + 2] + a_dst[n * HH + 2] + pae2 * inv_dc);
            float e0 = exp2f(sl0), e1 = exp2f(sl1), e2 = exp2f(sl2);
            unsigned ian = __umul24((unsigned)n, 96u) + lane;
            unsigned van = xs32[ian];
            float xn2 = bf2f(xsb[(ian << 1) + c128ml]);
            float r0 = __builtin_amdgcn_rcpf(pden0 + e0);
            float r1 = __builtin_amdgcn_rcpf(pden1 + e1);
            float r2 = __builtin_amdgcn_rcpf(pden2 + e2);
            OA[row * OAP +       lane] = f2bf((a0A + a0B + a0C + a0D + e0 * bf_lo(van)) * r0);
            OA[row * OAP +  64 + lane] = f2bf((a1A + a1B + a1C + a1D + e1 * bf_hi(van)) * r1);
            OA[row * OAP + 128 + lane] = f2bf((a2A + a2B + a2C + a2D + e2 * xn2) * r2);
        } else {
            if (t < 3) { pC.x = 0; pC.y = 0; pC.z = 0; pC.w = 0; }
            OA[row * OAP +       lane] = 0;
            OA[row * OAP +  64 + lane] = 0;
            OA[row * OAP + 128 + lane] = 0;
        }
        begC = begNx; degC = degNx;
    }
    __syncthreads();

    // ======== MLP phase: wave wid owns output cols wid*16..wid*16+15 ========
    int l15 = lane & 15, kg = (lane >> 4) * 8;
    int col = wid * 16 + l15;
    float cb1 = b1p[col], cg1 = g1[col], cbe1 = be1[col];
    float cb2 = b2[col],  cg2 = g2[col], cbe2 = be2[col];

    // GEMM1: [16 x 192] @ [192 x 16(cols of this wave)]
    f32x4 acc = (f32x4){0.f, 0.f, 0.f, 0.f};
    #pragma unroll
    for (int k0 = 0; k0 < HC; k0 += 32) {
        bf16x8 af = *(const bf16x8*)&OA[l15 * OAP + k0 + kg];
        bf16x8 bf = *(const bf16x8*)(w1t + (size_t)col * HC + k0 + kg);
        acc = __builtin_amdgcn_mfma_f32_16x16x32_bf16(af, bf, acc, 0, 0, 0);
    }

    int rj0 = (lane >> 4) * 4;
    float y[4], h1v[4];
    #pragma unroll
    for (int j = 0; j < 4; ++j) {
        int r = min(nb16 + rj0 + j, N - 1);
        y[j] = acc[j] + cb1 + x[(size_t)r * DIN + col];
        float s = y[j], q = y[j] * y[j];
        #pragma unroll
        for (int o = 1; o < 16; o <<= 1) {
            s += __shfl_xor(s, o, 64);
            q += __shfl_xor(q, o, 64);
        }
        if (l15 == 0) { red[0][wid][rj0 + j] = s; red[1][wid][rj0 + j] = q; }
    }
    __syncthreads();
    #pragma unroll
    for (int j = 0; j < 4; ++j) {
        int rj = rj0 + j;
        float s = red[0][0][rj] + red[0][1][rj] + red[0][2][rj] + red[0][3][rj];
        float q = red[1][0][rj] + red[1][1][rj] + red[1][2][rj] + red[1][3][rj];
        float m = s * (1.0f / CC);
        float var = q * (1.0f / CC) - m * m;
        float inv = rsqrtf(var + LN_EPS);
        float h = (y[j] - m) * inv * cg1 + cbe1;
        h1v[j] = h;
        H1s[rj * 72 + col] = f2bf(h);
    }
    __syncthreads();

    // GEMM2: [16 x 64] @ [64 x 16]
    f32x4 acc2 = (f32x4){0.f, 0.f, 0.f, 0.f};
    #pragma unroll
    for (int k0 = 0; k0 < CC; k0 += 32) {
        bf16x8 af = *(const bf16x8*)&H1s[l15 * 72 + k0 + kg];
        bf16x8 bf = *(const bf16x8*)(w2t + (size_t)col * CC + k0 + kg);
        acc2 = __builtin_amdgcn_mfma_f32_16x16x32_bf16(af, bf, acc2, 0, 0, 0);
    }

    float z[4];
    #pragma unroll
    for (int j = 0; j < 4; ++j) {
        z[j] = acc2[j] + cb2 + h1v[j];
        float s = z[j], q = z[j] * z[j];
        #pragma unroll
        for (int o = 1; o < 16; o <<= 1) {
            s += __shfl_xor(s, o, 64);
            q += __shfl_xor(q, o, 64);
        }
        if (l15 == 0) { red[0][wid][rj0 + j] = s; red[1][wid][rj0 + j] = q; }
    }
    __syncthreads();
    #pragma unroll
    for (int j = 0; j < 4; ++j) {
        int rj = rj0 + j;
        float s = red[0][0][rj] + red[0][1][rj] + red[0][2][rj] + red[0][3][rj];
        float q = red[1][0][rj] + red[1][1][rj] + red[1][2][rj] + red[1][3][rj];
        float m = s * (1.0f / CC);
        float var = q * (1.0f / CC) - m * m;
        float inv = rsqrtf(var + LN_EPS);
        int r = nb16 + rj;
        if (r < N)
            out[(size_t)r * CC + col] = (z[j] - m) * inv * cg2 + cbe2;
    }
}

extern "C" void kernel_launch(void* const* d_in, const int* in_sizes, int n_in,
                              void* d_out, int out_size, void* d_ws, size_t ws_size,
                              hipStream_t stream) {
    const float* x          = (const float*)d_in[0];
    const float* edge_attr  = (const float*)d_in[1];
    const float* lin_w      = (const float*)d_in[2];
    const float* att_src    = (const float*)d_in[3];
    const float* att_dst    = (const float*)d_in[4];
    const float* lin_edge_w = (const float*)d_in[5];
    const float* att_edge   = (const float*)d_in[6];
    const float* gat_bias   = (const float*)d_in[7];
    const float* w1         = (const float*)d_in[8];
    const float* b1         = (const float*)d_in[9];
    const float* ln1_g      = (const float*)d_in[10];
    const float* ln1_b      = (const float*)d_in[11];
    const float* w2         = (const float*)d_in[12];
    const float* b2         = (const float*)d_in[13];
    const float* ln2_g      = (const float*)d_in[14];
    const float* ln2_b      = (const float*)d_in[15];
    const int*   ei         = (const int*)d_in[16];
    float* out = (float*)d_out;

    const int N = in_sizes[0] / DIN;
    const int E = in_sizes[1] / ED;
    const int nb_scan = (N + 255) / 256;
    const int nbx = (N + 63) / 64;

    char* ws = (char*)d_ws;
    size_t off_b = 0;
    auto alloc = [&](size_t bytes) {
        size_t o = off_b;
        off_b = (off_b + bytes + 255) & ~(size_t)255;
        return o;
    };
    // zeroed region first (single memset)
    int* icnt = (int*)(ws + alloc((size_t)N * 4));
    int* gtot = (int*)(ws + alloc(4));
    size_t zero_bytes = off_b;
    // fully-overwritten region
    unsigned short* xsb = (unsigned short*)(ws + alloc((size_t)N * HC * 2));
    float*  a_srcb  = (float*)(ws + alloc((size_t)N * HH * 4));
    float*  a_dstb  = (float*)(ws + alloc((size_t)N * HH * 4));
    int*    offb    = (int*)(ws + alloc((size_t)N * 4));
    int*    cursor  = (int*)(ws + alloc((size_t)N * 4));
    uint4*  payload = (uint4*)(ws + alloc((size_t)E * 16));
    unsigned short* linwt = (unsigned short*)(ws + alloc((size_t)LWC * DIN * 2));
    unsigned short* w1t   = (unsigned short*)(ws + alloc((size_t)DIN * HC * 2));
    unsigned short* w2t   = (unsigned short*)(ws + alloc((size_t)CC * CC * 2));
    float* b1p = (float*)(ws + alloc((size_t)CC * 4));
    float* we  = (float*)(ws + alloc((size_t)ED * HH * 4));
    (void)ws_size; (void)n_in; (void)out_size;

    hipMemsetAsync(d_ws, 0, zero_bytes, stream);

    k_prep_cnt<<<PREP_BLOCKS + 1 + (E + 255) / 256, 256, 0, stream>>>(
        lin_w, w1, w2, b1, gat_bias, lin_edge_w, att_edge, att_src, att_dst,
        linwt, w1t, w2t, b1p, we, ei, icnt, E);
    k_xs<<<nbx + nb_scan, 256, 0, stream>>>(x, linwt, xsb, a_srcb, a_dstb,
                                            icnt, gtot, offb, cursor, N, nbx);
    k_fill<<<(E + 255) / 256, 256, 0, stream>>>(edge_attr, ei, a_srcb, a_dstb, we, cursor,
                                                payload, E);
    k_gatmlp<<<(N + 15) / 16, 256, 0, stream>>>(xsb, a_srcb, a_dstb, offb, icnt, payload,
                                                x, w1t, w2t, b1p, ln1_g, ln1_b,
                                                b2, ln2_g, ln2_b, out, N);
}

// Round 20
// 173.275 us; speedup vs baseline: 1.0415x; 1.0415x over previous
//
#include <hip/hip_runtime.h>

// GraphTransformerBlock2: GATConv(H=3,C=64, edge_dim=5, self-loops w/ mean fill)
// -> linear1 -> LN(x + .) -> linear2 -> LN(lin + .)
// All float32 I/O. edge_index int32 (2,E): src=ei[0:E], dst=ei[E:2E].
//
// R19 (consolidation of best-measured variants):
//  - k_gatmlp: R16/R17 3-wide phase B restored (R18's 4-wide pushed VGPR
//    36->40, occupancy 57->48%: TLP loss > ILP gain; 73.2 -> 78.3us).
//  - k_xs: R18's 13-tile MFMA fold kept (a_src/a_dst from MFMA tile 12,
//    no epilogue shuffle reductions).

#define HH 3
#define CC 64
#define DIN 64
#define ED 5
#define HC 192
#define LWC 208                 // extended linwt cols (13 tiles of 16)
#define OAP 200                 // padded OA row stride (u16)
#define NEG_SLOPE 0.2f
#define LN_EPS 1e-5f
#define LOG2E 1.44269504f

typedef __attribute__((ext_vector_type(8))) short bf16x8;
typedef __attribute__((ext_vector_type(4))) float f32x4;

__device__ __forceinline__ float leaky(float l) { return fmaxf(l, NEG_SLOPE * l); }

__device__ __forceinline__ unsigned short f2bf(float f) {
    unsigned u = __float_as_uint(f);
    unsigned r = (u + 0x7FFFu + ((u >> 16) & 1u)) >> 16;   // RNE
    return (unsigned short)r;
}
__device__ __forceinline__ float bf2f(unsigned short u) {
    return __uint_as_float((unsigned)u << 16);
}
__device__ __forceinline__ float bf_lo(unsigned v) { return __uint_as_float(v << 16); }
__device__ __forceinline__ float bf_hi(unsigned v) { return __uint_as_float(v & 0xFFFF0000u); }

__device__ __forceinline__ bf16x8 pack8(float4 a, float4 b) {
    bf16x8 r;
    r[0] = (short)f2bf(a.x); r[1] = (short)f2bf(a.y);
    r[2] = (short)f2bf(a.z); r[3] = (short)f2bf(a.w);
    r[4] = (short)f2bf(b.x); r[5] = (short)f2bf(b.y);
    r[6] = (short)f2bf(b.z); r[7] = (short)f2bf(b.w);
    return r;
}

// ---------- prep: transposes (blocks 0..27), folds (block 28), cnt (rest) ----------
#define PREP_TRANS (HC*DIN + DIN*HC + CC*CC)
#define PREP_BLOCKS 28
__global__ __launch_bounds__(256) void k_prep_cnt(const float* __restrict__ lin_w,
                                                  const float* __restrict__ w1,
                                                  const float* __restrict__ w2,
                                                  const float* __restrict__ b1,
                                                  const float* __restrict__ gat_bias,
                                                  const float* __restrict__ lin_edge_w,
                                                  const float* __restrict__ att_edge,
                                                  const float* __restrict__ att_src,
                                                  const float* __restrict__ att_dst,
                                                  unsigned short* __restrict__ linwt,
                                                  unsigned short* __restrict__ w1t,
                                                  unsigned short* __restrict__ w2t,
                                                  float* __restrict__ b1p,
                                                  float* __restrict__ we,
                                                  const int* __restrict__ ei,
                                                  int* __restrict__ icnt, int E) {
    if (blockIdx.x < PREP_BLOCKS) {
        for (int i = blockIdx.x * 256 + threadIdx.x; i < PREP_TRANS; i += PREP_BLOCKS * 256) {
            if (i < HC * DIN) {
                int c = i >> 6, k = i & 63;
                linwt[i] = f2bf(lin_w[k * HC + c]);
            } else if (i < 2 * HC * DIN) {
                int j = i - HC * DIN;
                int c = j / HC, k = j - c * HC;
                w1t[j] = f2bf(w1[k * CC + c]);
            } else {
                int j = i - 2 * HC * DIN;
                int c = j >> 6, k = j & 63;
                w2t[j] = f2bf(w2[k * CC + c]);
            }
        }
    } else if (blockIdx.x == PREP_BLOCKS) {
        __shared__ float pb[4][CC];
        __shared__ float pw[15][16];
        int t = threadIdx.x;
        int c = t & 63, kq = t >> 6;
        float s = 0.f;
        for (int k = kq * 48; k < kq * 48 + 48; ++k)
            s += gat_bias[k] * w1[k * CC + c];
        pb[kq][c] = s;
        int q = t >> 4, cq = t & 15;
        if (q < 15) {
            int d = q / HH, h = q - d * HH;
            float s2 = 0.f;
            #pragma unroll
            for (int c2 = cq * 4; c2 < cq * 4 + 4; ++c2)
                s2 += lin_edge_w[d * HC + h * CC + c2] * att_edge[h * CC + c2];
            pw[q][cq] = s2;
        }
        // extended linwt cols 192..207: wsf (a_src fold), wdf (a_dst fold), zeros
        for (int idx = t; idx < 16 * DIN; idx += 256) {
            int col = idx >> 6;          // 0..15
            int d = idx & 63;
            float v = 0.f;
            if (col < 6) {
                int h = (col < 3) ? col : col - 3;
                const float* att = (col < 3) ? att_src : att_dst;
                for (int c2 = 0; c2 < CC; ++c2)
                    v += lin_w[d * HC + h * CC + c2] * att[h * CC + c2];
                v *= LOG2E;
            }
            linwt[(size_t)(HC + col) * DIN + d] = f2bf(v);
        }
        __syncthreads();
        if (t < CC) b1p[t] = b1[t] + pb[0][t] + pb[1][t] + pb[2][t] + pb[3][t];
        if (t < 15) {
            float tot = 0.f;
            #pragma unroll
            for (int i2 = 0; i2 < 16; ++i2) tot += pw[t][i2];
            we[t] = tot * LOG2E;
        }
    } else {
        int nb = gridDim.x - PREP_BLOCKS - 1;
        for (int e = (blockIdx.x - PREP_BLOCKS - 1) * 256 + threadIdx.x; e < E; e += nb * 256)
            atomicAdd(&icnt[ei[E + e]], 1);
    }
}

// ---------- xs = x @ [lin_w | folds] (MFMA, 13 tiles) -> xsb + a_src/a_dst; scan fused ----------
__global__ __launch_bounds__(256) void k_xs(const float* __restrict__ x,
                                            const unsigned short* __restrict__ linwt,
                                            unsigned short* __restrict__ xsb,
                                            float* __restrict__ a_src,
                                            float* __restrict__ a_dst,
                                            const int* __restrict__ icnt,
                                            int* __restrict__ gtot,
                                            int* __restrict__ off,
                                            int* __restrict__ cursor,
                                            int N, int nbx) {
    __shared__ int wt[4];
    __shared__ int base_sh;
    if ((int)blockIdx.x >= nbx) {
        int bid = blockIdx.x - nbx;
        int i = bid * 256 + threadIdx.x;
        int lane = threadIdx.x & 63, wid = threadIdx.x >> 6;
        int v = (i < N) ? icnt[i] : 0;
        int incl = v;
        #pragma unroll
        for (int o = 1; o < 64; o <<= 1) {
            int u = __shfl_up(incl, o, 64);
            if (lane >= o) incl += u;
        }
        if (lane == 63) wt[wid] = incl;
        __syncthreads();
        if (threadIdx.x == 0)
            base_sh = atomicAdd(gtot, wt[0] + wt[1] + wt[2] + wt[3]);
        __syncthreads();
        int wpre = 0;
        for (int w2 = 0; w2 < wid; ++w2) wpre += wt[w2];
        int excl = base_sh + wpre + incl - v;
        if (i < N) { off[i] = excl; cursor[i] = excl; }
        return;
    }

    int lane = threadIdx.x & 63, w = threadIdx.x >> 6;
    int l15 = lane & 15, kg = (lane >> 4) * 8;
    int nb = blockIdx.x * 64;
    int arow = nb + w * 16 + l15;
    int arow_c = min(arow, N - 1);

    f32x4 acc[13];
    #pragma unroll
    for (int ct = 0; ct < 13; ++ct) acc[ct] = (f32x4){0.f, 0.f, 0.f, 0.f};

    #pragma unroll
    for (int k0 = 0; k0 < DIN; k0 += 32) {
        const float* ap = x + (size_t)arow_c * DIN + k0 + kg;
        float4 a0 = *(const float4*)ap;
        float4 a1 = *(const float4*)(ap + 4);
        bf16x8 af = pack8(a0, a1);
        #pragma unroll
        for (int ct = 0; ct < 13; ++ct) {
            bf16x8 bf = *(const bf16x8*)(linwt + (size_t)(ct * 16 + l15) * DIN + k0 + kg);
            acc[ct] = __builtin_amdgcn_mfma_f32_16x16x32_bf16(af, bf, acc[ct], 0, 0, 0);
        }
    }

    int rbase = nb + w * 16 + (lane >> 4) * 4;
    #pragma unroll
    for (int j = 0; j < 4; ++j) {
        int r = rbase + j;
        bool ok = r < N;
        if (ok) {
            unsigned* row32 = (unsigned*)(xsb + (size_t)r * HC);
            #pragma unroll
            for (int ct = 0; ct < 4; ++ct) {
                int c = ct * 16 + l15;
                row32[c] = (unsigned)f2bf(acc[ct][j]) | ((unsigned)f2bf(acc[ct + 4][j]) << 16);
                xsb[(size_t)r * HC + 128 + c] = f2bf(acc[ct + 8][j]);
            }
            // tile 12: cols 192..197 = a_src[0..2], a_dst[0..2] (pre-scaled by log2e)
            if (l15 < 3)           a_src[r * HH + l15] = acc[12][j];
            else if (l15 < 6)      a_dst[r * HH + (l15 - 3)] = acc[12][j];
        }
    }
}

// ---------- payload fill (CSR order), 16B/edge, a_dst FOLDED IN ----------
__global__ __launch_bounds__(256) void k_fill(const float* __restrict__ ea,
                                              const int* __restrict__ ei,
                                              const float* __restrict__ a_src,
                                              const float* __restrict__ a_dst,
                                              const float* __restrict__ we,
                                              int* __restrict__ cursor,
                                              uint4* __restrict__ payload, int E) {
    int e = blockIdx.x * blockDim.x + threadIdx.x;
    if (e >= E) return;
    int s = ei[e], d = ei[E + e];
    int pos = atomicAdd(&cursor[d], 1);                  // issue early; hide RMW latency
    float attr[ED];
    #pragma unroll
    for (int j = 0; j < ED; ++j) attr[j] = ea[(size_t)e * ED + j];
    float aeh[HH], lp[HH];
    #pragma unroll
    for (int h = 0; h < HH; ++h) {
        float a = 0.f;
        #pragma unroll
        for (int j = 0; j < ED; ++j) a += attr[j] * we[j * HH + h];   // we pre-scaled
        aeh[h] = a;
        lp[h] = a_src[s * HH + h] + a_dst[d * HH + h] + a;             // all pre-scaled
    }
    uint4 pk;
    pk.x = (unsigned)f2bf(lp[0])  | ((unsigned)f2bf(lp[1])  << 16);
    pk.y = (unsigned)f2bf(lp[2])  | ((unsigned)f2bf(aeh[0]) << 16);
    pk.z = (unsigned)f2bf(aeh[1]) | ((unsigned)f2bf(aeh[2]) << 16);
    pk.w = (unsigned)s;
    payload[pos] = pk;
}

// ---------- FUSED: per-dst softmax+gather (pipelined, 3-wide) -> MLP -> out ----------
__global__ __launch_bounds__(256) void k_gatmlp(const unsigned short* __restrict__ xsb,
                                                const float* __restrict__ a_src,
                                                const float* __restrict__ a_dst,
                                                const int* __restrict__ off,
                                                const int* __restrict__ icnt,
                                                const uint4* __restrict__ payload,
                                                const float* __restrict__ x,
                                                const unsigned short* __restrict__ w1t,
                                                const unsigned short* __restrict__ w2t,
                                                const float* __restrict__ b1p,
                                                const float* __restrict__ g1,
                                                const float* __restrict__ be1,
                                                const float* __restrict__ b2,
                                                const float* __restrict__ g2,
                                                const float* __restrict__ be2,
                                                float* __restrict__ out, int N) {
    __shared__ float4 wbuf[4][64];                 // 4 KB
    __shared__ unsigned short OA[16 * OAP];        // 6.25 KB, padded stride
    __shared__ unsigned short H1s[16 * 72];        // 2.25 KB
    __shared__ float red[2][4][16];                // 512 B
    int lane = threadIdx.x & 63;
    int wid  = threadIdx.x >> 6;
    const unsigned* xs32 = (const unsigned*)xsb;
    unsigned c128ml = 128u - (unsigned)lane;
    int nb16 = blockIdx.x * 16;
    int n0 = nb16 + wid * 4;

    // ---- pipeline prologue: node 0's descriptor + first payload chunk ----
    int begC = 0, degC = 0;
    if (n0 < N) { begC = off[n0]; degC = icnt[n0]; }
    uint4 pC; pC.x = 0; pC.y = 0; pC.z = 0; pC.w = 0;
    if (lane < degC) pC = payload[begC + lane];

    // ======== gather phase: 4 nodes, software-pipelined, 3-wide phase B ========
    #pragma unroll 1
    for (int t = 0; t < 4; ++t) {
        int row = wid * 4 + t;
        int n = n0 + t;
        int begNx = 0, degNx = 0;
        if (t < 3) {
            int nn = n + 1;
            if (nn < N) { begNx = off[nn]; degNx = icnt[nn]; }
        }
        int beg = begC, deg = degC;
        uint4 p0 = pC;

        if (n < N) {
            float pden0 = 0.f, pden1 = 0.f, pden2 = 0.f;
            float pae0 = 0.f, pae1 = 0.f, pae2 = 0.f;
            float a0A = 0.f, a1A = 0.f, a2A = 0.f;
            float a0B = 0.f, a1B = 0.f, a2B = 0.f;
            float a0C = 0.f, a1C = 0.f, a2C = 0.f;

            // ---- chunk 0 (peeled, payload already in p0) ----
            {
                int cn = min(deg, 64);
                float w0 = 0.f, w1 = 0.f, w2 = 0.f;
                int src = 0;
                if (lane < cn) {
                    w0 = exp2f(leaky(bf_lo(p0.x)));
                    w1 = exp2f(leaky(bf_hi(p0.x)));
                    w2 = exp2f(leaky(bf_lo(p0.y)));
                    pae0 += bf_hi(p0.y);
                    pae1 += bf_lo(p0.z);
                    pae2 += bf_hi(p0.z);
                    pden0 += w0; pden1 += w1; pden2 += w2;
                    src = (int)p0.w;
                }
                wbuf[wid][lane] = make_float4(w0, w1, w2, __int_as_float(src));
                if (t < 3) {
                    pC.x = 0; pC.y = 0; pC.z = 0; pC.w = 0;
                    if (lane < degNx) pC = payload[begNx + lane];
                }
                int i = 0;
                for (; i + 3 <= cn; i += 3) {
                    float4 ta = wbuf[wid][i];
                    float4 tb = wbuf[wid][i + 1];
                    float4 tc = wbuf[wid][i + 2];
                    unsigned ia = __umul24((unsigned)__float_as_int(ta.w), 96u) + lane;
                    unsigned ib = __umul24((unsigned)__float_as_int(tb.w), 96u) + lane;
                    unsigned ic = __umul24((unsigned)__float_as_int(tc.w), 96u) + lane;
                    unsigned va = xs32[ia];
                    unsigned vb = xs32[ib];
                    unsigned vc = xs32[ic];
                    float xa2 = bf2f(xsb[(ia << 1) + c128ml]);
                    float xb2 = bf2f(xsb[(ib << 1) + c128ml]);
                    float xc2 = bf2f(xsb[(ic << 1) + c128ml]);
                    a0A += ta.x * bf_lo(va); a1A += ta.y * bf_hi(va); a2A += ta.z * xa2;
                    a0B += tb.x * bf_lo(vb); a1B += tb.y * bf_hi(vb); a2B += tb.z * xb2;
                    a0C += tc.x * bf_lo(vc); a1C += tc.y * bf_hi(vc); a2C += tc.z * xc2;
                }
                for (; i < cn; ++i) {
                    float4 ta = wbuf[wid][i];
                    unsigned ia = __umul24((unsigned)__float_as_int(ta.w), 96u) + lane;
                    unsigned va = xs32[ia];
                    a0A += ta.x * bf_lo(va);
                    a1A += ta.y * bf_hi(va);
                    a2A += ta.z * bf2f(xsb[(ia << 1) + c128ml]);
                }
            }
            // ---- remaining chunks (rare: deg > 64) ----
            for (int c0 = 64; c0 < deg; c0 += 64) {
                int cn = min(deg - c0, 64);
                float w0 = 0.f, w1 = 0.f, w2 = 0.f;
                int src = 0;
                if (lane < cn) {
                    uint4 p = payload[beg + c0 + lane];
                    w0 = exp2f(leaky(bf_lo(p.x)));
                    w1 = exp2f(leaky(bf_hi(p.x)));
                    w2 = exp2f(leaky(bf_lo(p.y)));
                    pae0 += bf_hi(p.y);
                    pae1 += bf_lo(p.z);
                    pae2 += bf_hi(p.z);
                    pden0 += w0; pden1 += w1; pden2 += w2;
                    src = (int)p.w;
                }
                wbuf[wid][lane] = make_float4(w0, w1, w2, __int_as_float(src));
                int i = 0;
                for (; i + 3 <= cn; i += 3) {
                    float4 ta = wbuf[wid][i];
                    float4 tb = wbuf[wid][i + 1];
                    float4 tc = wbuf[wid][i + 2];
                    unsigned ia = __umul24((unsigned)__float_as_int(ta.w), 96u) + lane;
                    unsigned ib = __umul24((unsigned)__float_as_int(tb.w), 96u) + lane;
                    unsigned ic = __umul24((unsigned)__float_as_int(tc.w), 96u) + lane;
                    unsigned va = xs32[ia];
                    unsigned vb = xs32[ib];
                    unsigned vc = xs32[ic];
                    float xa2 = bf2f(xsb[(ia << 1) + c128ml]);
                    float xb2 = bf2f(xsb[(ib << 1) + c128ml]);
                    float xc2 = bf2f(xsb[(ic << 1) + c128ml]);
                    a0A += ta.x * bf_lo(va); a1A += ta.y * bf_hi(va); a2A += ta.z * xa2;
                    a0B += tb.x * bf_lo(vb); a1B += tb.y * bf_hi(vb); a2B += tb.z * xb2;
                    a0C += tc.x * bf_lo(vc); a1C += tc.y * bf_hi(vc); a2C += tc.z * xc2;
                }
                for (; i < cn; ++i) {
                    float4 ta = wbuf[wid][i];
                    unsigned ia = __umul24((unsigned)__float_as_int(ta.w), 96u) + lane;
                    unsigned va = xs32[ia];
                    a0A += ta.x * bf_lo(va);
                    a1A += ta.y * bf_hi(va);
                    a2A += ta.z * bf2f(xsb[(ia << 1) + c128ml]);
                }
            }

            #pragma unroll
            for (int o = 32; o; o >>= 1) {
                pden0 += __shfl_xor(pden0, o, 64);
                pden1 += __shfl_xor(pden1, o, 64);
                pden2 += __shfl_xor(pden2, o, 64);
                pae0  += __shfl_xor(pae0, o, 64);
                pae1  += __shfl_xor(pae1, o, 64);
                pae2  += __shfl_xor(pae2, o, 64);
            }

            float dc = fmaxf((float)deg, 1.0f);
            float inv_dc = __builtin_amdgcn_rcpf(dc);
            float sl0 = leaky(a_src[n * HH + 0] + a_dst[n * HH + 0] + pae0 * inv_dc);
            float sl1 = leaky(a_src[n * HH + 1] + a_dst[n * HH + 1] + pae1 * inv_dc);
            float sl2 = leaky(a_src[n * HH + 2] + a_dst[n * HH + 2] + pae2 * inv_dc);
            float e0 = exp2f(sl0), e1 = exp2f(sl1), e2 = exp2f(sl2);
            unsigned ian = __umul24((unsigned)n, 96u) + lane;
            unsigned van = xs32[ian];
            float xn2 = bf2f(xsb[(ian << 1) + c128ml]);
            float r0 = __builtin_amdgcn_rcpf(pden0 + e0);
            float r1 = __builtin_amdgcn_rcpf(pden1 + e1);
            float r2 = __builtin_amdgcn_rcpf(pden2 + e2);
            OA[row * OAP +       lane] = f2bf((a0A + a0B + a0C + e0 * bf_lo(van)) * r0);
            OA[row * OAP +  64 + lane] = f2bf((a1A + a1B + a1C + e1 * bf_hi(van)) * r1);
            OA[row * OAP + 128 + lane] = f2bf((a2A + a2B + a2C + e2 * xn2) * r2);
        } else {
            if (t < 3) { pC.x = 0; pC.y = 0; pC.z = 0; pC.w = 0; }
            OA[row * OAP +       lane] = 0;
            OA[row * OAP +  64 + lane] = 0;
            OA[row * OAP + 128 + lane] = 0;
        }
        begC = begNx; degC = degNx;
    }
    __syncthreads();

    // ======== MLP phase: wave wid owns output cols wid*16..wid*16+15 ========
    int l15 = lane & 15, kg = (lane >> 4) * 8;
    int col = wid * 16 + l15;
    float cb1 = b1p[col], cg1 = g1[col], cbe1 = be1[col];
    float cb2 = b2[col],  cg2 = g2[col], cbe2 = be2[col];

    // GEMM1: [16 x 192] @ [192 x 16(cols of this wave)]
    f32x4 acc = (f32x4){0.f, 0.f, 0.f, 0.f};
    #pragma unroll
    for (int k0 = 0; k0 < HC; k0 += 32) {
        bf16x8 af = *(const bf16x8*)&OA[l15 * OAP + k0 + kg];
        bf16x8 bf = *(const bf16x8*)(w1t + (size_t)col * HC + k0 + kg);
        acc = __builtin_amdgcn_mfma_f32_16x16x32_bf16(af, bf, acc, 0, 0, 0);
    }

    int rj0 = (lane >> 4) * 4;
    float y[4], h1v[4];
    #pragma unroll
    for (int j = 0; j < 4; ++j) {
        int r = min(nb16 + rj0 + j, N - 1);
        y[j] = acc[j] + cb1 + x[(size_t)r * DIN + col];
        float s = y[j], q = y[j] * y[j];
        #pragma unroll
        for (int o = 1; o < 16; o <<= 1) {
            s += __shfl_xor(s, o, 64);
            q += __shfl_xor(q, o, 64);
        }
        if (l15 == 0) { red[0][wid][rj0 + j] = s; red[1][wid][rj0 + j] = q; }
    }
    __syncthreads();
    #pragma unroll
    for (int j = 0; j < 4; ++j) {
        int rj = rj0 + j;
        float s = red[0][0][rj] + red[0][1][rj] + red[0][2][rj] + red[0][3][rj];
        float q = red[1][0][rj] + red[1][1][rj] + red[1][2][rj] + red[1][3][rj];
        float m = s * (1.0f / CC);
        float var = q * (1.0f / CC) - m * m;
        float inv = rsqrtf(var + LN_EPS);
        float h = (y[j] - m) * inv * cg1 + cbe1;
        h1v[j] = h;
        H1s[rj * 72 + col] = f2bf(h);
    }
    __syncthreads();

    // GEMM2: [16 x 64] @ [64 x 16]
    f32x4 acc2 = (f32x4){0.f, 0.f, 0.f, 0.f};
    #pragma unroll
    for (int k0 = 0; k0 < CC; k0 += 32) {
        bf16x8 af = *(const bf16x8*)&H1s[l15 * 72 + k0 + kg];
        bf16x8 bf = *(const bf16x8*)(w2t + (size_t)col * CC + k0 + kg);
        acc2 = __builtin_amdgcn_mfma_f32_16x16x32_bf16(af, bf, acc2, 0, 0, 0);
    }

    float z[4];
    #pragma unroll
    for (int j = 0; j < 4; ++j) {
        z[j] = acc2[j] + cb2 + h1v[j];
        float s = z[j], q = z[j] * z[j];
        #pragma unroll
        for (int o = 1; o < 16; o <<= 1) {
            s += __shfl_xor(s, o, 64);
            q += __shfl_xor(q, o, 64);
        }
        if (l15 == 0) { red[0][wid][rj0 + j] = s; red[1][wid][rj0 + j] = q; }
    }
    __syncthreads();
    #pragma unroll
    for (int j = 0; j < 4; ++j) {
        int rj = rj0 + j;
        float s = red[0][0][rj] + red[0][1][rj] + red[0][2][rj] + red[0][3][rj];
        float q = red[1][0][rj] + red[1][1][rj] + red[1][2][rj] + red[1][3][rj];
        float m = s * (1.0f / CC);
        float var = q * (1.0f / CC) - m * m;
        float inv = rsqrtf(var + LN_EPS);
        int r = nb16 + rj;
        if (r < N)
            out[(size_t)r * CC + col] = (z[j] - m) * inv * cg2 + cbe2;
    }
}

extern "C" void kernel_launch(void* const* d_in, const int* in_sizes, int n_in,
                              void* d_out, int out_size, void* d_ws, size_t ws_size,
                              hipStream_t stream) {
    const float* x          = (const float*)d_in[0];
    const float* edge_attr  = (const float*)d_in[1];
    const float* lin_w      = (const float*)d_in[2];
    const float* att_src    = (const float*)d_in[3];
    const float* att_dst    = (const float*)d_in[4];
    const float* lin_edge_w = (const float*)d_in[5];
    const float* att_edge   = (const float*)d_in[6];
    const float* gat_bias   = (const float*)d_in[7];
    const float* w1         = (const float*)d_in[8];
    const float* b1         = (const float*)d_in[9];
    const float* ln1_g      = (const float*)d_in[10];
    const float* ln1_b      = (const float*)d_in[11];
    const float* w2         = (const float*)d_in[12];
    const float* b2         = (const float*)d_in[13];
    const float* ln2_g      = (const float*)d_in[14];
    const float* ln2_b      = (const float*)d_in[15];
    const int*   ei         = (const int*)d_in[16];
    float* out = (float*)d_out;

    const int N = in_sizes[0] / DIN;
    const int E = in_sizes[1] / ED;
    const int nb_scan = (N + 255) / 256;
    const int nbx = (N + 63) / 64;

    char* ws = (char*)d_ws;
    size_t off_b = 0;
    auto alloc = [&](size_t bytes) {
        size_t o = off_b;
        off_b = (off_b + bytes + 255) & ~(size_t)255;
        return o;
    };
    // zeroed region first (single memset)
    int* icnt = (int*)(ws + alloc((size_t)N * 4));
    int* gtot = (int*)(ws + alloc(4));
    size_t zero_bytes = off_b;
    // fully-overwritten region
    unsigned short* xsb = (unsigned short*)(ws + alloc((size_t)N * HC * 2));
    float*  a_srcb  = (float*)(ws + alloc((size_t)N * HH * 4));
    float*  a_dstb  = (float*)(ws + alloc((size_t)N * HH * 4));
    int*    offb    = (int*)(ws + alloc((size_t)N * 4));
    int*    cursor  = (int*)(ws + alloc((size_t)N * 4));
    uint4*  payload = (uint4*)(ws + alloc((size_t)E * 16));
    unsigned short* linwt = (unsigned short*)(ws + alloc((size_t)LWC * DIN * 2));
    unsigned short* w1t   = (unsigned short*)(ws + alloc((size_t)DIN * HC * 2));
    unsigned short* w2t   = (unsigned short*)(ws + alloc((size_t)CC * CC * 2));
    float* b1p = (float*)(ws + alloc((size_t)CC * 4));
    float* we  = (float*)(ws + alloc((size_t)ED * HH * 4));
    (void)ws_size; (void)n_in; (void)out_size;

    hipMemsetAsync(d_ws, 0, zero_bytes, stream);

    k_prep_cnt<<<PREP_BLOCKS + 1 + (E + 255) / 256, 256, 0, stream>>>(
        lin_w, w1, w2, b1, gat_bias, lin_edge_w, att_edge, att_src, att_dst,
        linwt, w1t, w2t, b1p, we, ei, icnt, E);
    k_xs<<<nbx + nb_scan, 256, 0, stream>>>(x, linwt, xsb, a_srcb, a_dstb,
                                            icnt, gtot, offb, cursor, N, nbx);
    k_fill<<<(E + 255) / 256, 256, 0, stream>>>(edge_attr, ei, a_srcb, a_dstb, we, cursor,
                                                payload, E);
    k_gatmlp<<<(N + 15) / 16, 256, 0, stream>>>(xsb, a_srcb, a_dstb, offb, icnt, payload,
                                                x, w1t, w2t, b1p, ln1_g, ln1_b,
                                                b2, ln2_g, ln2_b, out, N);
}